// Round 3
// baseline (419.218 us; speedup 1.0000x reference)
//
#include <hip/hip_runtime.h>
#include <cstdint>
#include <cstddef>

#define ROWS 27648
#define NEGV (-1e10f)

typedef __attribute__((ext_vector_type(8))) short bf16x8;
typedef __attribute__((ext_vector_type(4))) short short4v;
typedef __attribute__((ext_vector_type(4))) float f32x4;

__device__ __forceinline__ float sigmoidf_(float x) { return 1.f / (1.f + __expf(-x)); }
__device__ __forceinline__ float bf2f(short s) {
  union { float f; unsigned u; } x; x.u = ((unsigned)(unsigned short)s) << 16; return x.f;
}
__device__ __forceinline__ short f2bf(float f) {   // RNE
  union { float f; unsigned u; } x; x.f = f;
  unsigned r = (x.u + 0x7fffu + ((x.u >> 16) & 1u)) >> 16;
  return (short)r;
}

// ---------------------------------------------------------------------------
// bf16 MFMA GEMM: C = act(A @ B^T + bias); 128x128 tile, BK=32, 256 thr.
// Grid: (216 row-tiles, n col-tiles): same-A-slab blocks are id-congruent
// mod 8 => same XCD L2.
// ---------------------------------------------------------------------------
#define GLDS(gp, lp) __builtin_amdgcn_global_load_lds( \
  (const __attribute__((address_space(1))) void*)(gp), \
  (__attribute__((address_space(3))) void*)(lp), 16, 0, 0)

template <int ACT, int BF16OUT>
__global__ __launch_bounds__(256) void gemm_mfma(
    const short* __restrict__ A, int lda,
    const short* __restrict__ B, int ldb,
    const float* __restrict__ bias,
    void* __restrict__ Cv, int ldc, int nstore, int K) {
  __shared__ short As[128 * 32];
  __shared__ short Bs[128 * 32];
  const int tid = threadIdx.x;
  const int wave = tid >> 6, lane = tid & 63;
  const int m0 = blockIdx.x * 128, n0 = blockIdx.y * 128;
  const int srow = lane >> 2, scol = (lane & 3) * 8;
  const int sr0 = wave * 32;
  const int wm = (wave >> 1) * 64, wn = (wave & 1) * 64;
  const int fr = lane & 15, fk = (lane >> 4) * 8;

  f32x4 acc[4][4] = {};

  const short* pA0 = A + (size_t)(m0 + sr0 + srow) * lda + scol;
  const short* pA1 = pA0 + 16 * lda;
  const short* pB0 = B + (size_t)(n0 + sr0 + srow) * ldb + scol;
  const short* pB1 = pB0 + 16 * ldb;
  short* lA0 = &As[sr0 * 32];
  short* lA1 = &As[(sr0 + 16) * 32];
  short* lB0 = &Bs[sr0 * 32];
  short* lB1 = &Bs[(sr0 + 16) * 32];

  for (int k0 = 0; k0 < K; k0 += 32) {
    GLDS(pA0 + k0, lA0);
    GLDS(pA1 + k0, lA1);
    GLDS(pB0 + k0, lB0);
    GLDS(pB1 + k0, lB1);
    __syncthreads();
    bf16x8 af[4], bfr[4];
#pragma unroll
    for (int t = 0; t < 4; ++t) {
      af[t]  = *(const bf16x8*)&As[(wm + t * 16 + fr) * 32 + fk];
      bfr[t] = *(const bf16x8*)&Bs[(wn + t * 16 + fr) * 32 + fk];
    }
#pragma unroll
    for (int i = 0; i < 4; ++i)
#pragma unroll
      for (int j = 0; j < 4; ++j)
        acc[i][j] = __builtin_amdgcn_mfma_f32_16x16x32_bf16(af[i], bfr[j], acc[i][j], 0, 0, 0);
    __syncthreads();
  }

  const int rbase = m0 + wm + (lane >> 4) * 4;
#pragma unroll
  for (int j = 0; j < 4; ++j) {
    const int col = n0 + wn + j * 16 + fr;
    if (col >= nstore) continue;
    const float bv = bias ? bias[col] : 0.f;
#pragma unroll
    for (int i = 0; i < 4; ++i)
#pragma unroll
      for (int r = 0; r < 4; ++r) {
        const int row = rbase + i * 16 + r;
        float v = acc[i][j][r] + bv;
        if (ACT) v = fmaxf(v, 0.f);
        if (BF16OUT) ((short*)Cv)[(size_t)row * ldc + col] = f2bf(v);
        else         ((float*)Cv)[(size_t)row * ldc + col] = v;
      }
  }
}

// ---------------------------------------------------------------------------
// Split-output GEMM for [P1 | QK].
// ---------------------------------------------------------------------------
__global__ __launch_bounds__(256) void gemm_pqk(
    const short* __restrict__ A, const short* __restrict__ B,
    const float* __restrict__ bias,
    short* __restrict__ P1, float* __restrict__ QK) {
  __shared__ short As[128 * 32];
  __shared__ short Bs[128 * 32];
  const int tid = threadIdx.x;
  const int wave = tid >> 6, lane = tid & 63;
  const int m0 = blockIdx.x * 128, n0 = blockIdx.y * 128;
  const int srow = lane >> 2, scol = (lane & 3) * 8;
  const int sr0 = wave * 32;
  const int wm = (wave >> 1) * 64, wn = (wave & 1) * 64;
  const int fr = lane & 15, fk = (lane >> 4) * 8;

  f32x4 acc[4][4] = {};
  const short* pA0 = A + (size_t)(m0 + sr0 + srow) * 288 + scol;
  const short* pA1 = pA0 + 16 * 288;
  const short* pB0 = B + (size_t)(n0 + sr0 + srow) * 256 + scol;
  const short* pB1 = pB0 + 16 * 256;
  short* lA0 = &As[sr0 * 32];
  short* lA1 = &As[(sr0 + 16) * 32];
  short* lB0 = &Bs[sr0 * 32];
  short* lB1 = &Bs[(sr0 + 16) * 32];

  for (int k0 = 0; k0 < 256; k0 += 32) {
    GLDS(pA0 + k0, lA0);
    GLDS(pA1 + k0, lA1);
    GLDS(pB0 + k0, lB0);
    GLDS(pB1 + k0, lB1);
    __syncthreads();
    bf16x8 af[4], bfr[4];
#pragma unroll
    for (int t = 0; t < 4; ++t) {
      af[t]  = *(const bf16x8*)&As[(wm + t * 16 + fr) * 32 + fk];
      bfr[t] = *(const bf16x8*)&Bs[(wn + t * 16 + fr) * 32 + fk];
    }
#pragma unroll
    for (int i = 0; i < 4; ++i)
#pragma unroll
      for (int j = 0; j < 4; ++j)
        acc[i][j] = __builtin_amdgcn_mfma_f32_16x16x32_bf16(af[i], bfr[j], acc[i][j], 0, 0, 0);
    __syncthreads();
  }

  const int rbase = m0 + wm + (lane >> 4) * 4;
#pragma unroll
  for (int j = 0; j < 4; ++j) {
    const int col = n0 + wn + j * 16 + fr;
    if (col >= 384) continue;
    const float bv = bias[col];
#pragma unroll
    for (int i = 0; i < 4; ++i)
#pragma unroll
      for (int r = 0; r < 4; ++r) {
        const int row = rbase + i * 16 + r;
        float v = acc[i][j][r] + bv;
        if (col < 256) {
          P1[(size_t)row * 256 + col] = f2bf(fmaxf(v, 0.f));
        } else {
          QK[(size_t)row * 128 + (col - 256)] = v;
        }
      }
  }
}

// ---------------------------------------------------------------------------
// Activation conversion.
// ---------------------------------------------------------------------------
__global__ __launch_bounds__(256) void conv_acts(
    const float* __restrict__ inputs, const float* __restrict__ hidden,
    short* __restrict__ xin, short* __restrict__ hid) {
  const int NX = ROWS * 352;
  int idx = blockIdx.x * 256 + threadIdx.x;
  if (idx < NX) {
    int row = idx / 352, c = idx - row * 352;
    xin[idx] = (c < 322) ? f2bf(inputs[row * 322 + c]) : (short)0;
  } else {
    int j = idx - NX;
    if (j < ROWS * 256) hid[j] = f2bf(hidden[j]);
  }
}

// ---------------------------------------------------------------------------
// Weight conversion / packing.
// ---------------------------------------------------------------------------
__global__ __launch_bounds__(256) void conv_w(
    const float* __restrict__ W1, const float* __restrict__ Wih,
    const float* __restrict__ Whh, const float* __restrict__ Wp1,
    const float* __restrict__ Wp2, const float* __restrict__ Wq,
    const float* __restrict__ Wk, const float* __restrict__ Wg1,
    const float* __restrict__ Wd1, const float* __restrict__ Wg2,
    const float* __restrict__ Wd2, const float* __restrict__ bp1,
    const float* __restrict__ bq, const float* __restrict__ bg1,
    const float* __restrict__ bd1, const float* __restrict__ bg2,
    const float* __restrict__ bd2,
    short* __restrict__ w1w, short* __restrict__ wihw, short* __restrict__ whhw,
    short* __restrict__ wp2w, short* __restrict__ wpqk, short* __restrict__ wgdw,
    short* __restrict__ wfw, float* __restrict__ bpqkb, float* __restrict__ bgd,
    float* __restrict__ bf2v) {
  int idx = blockIdx.x * 256 + threadIdx.x;
  if (idx < 90112) {
    int r = idx / 352, c = idx - r * 352;
    w1w[idx] = (c < 322) ? f2bf(W1[r * 322 + c]) : (short)0;
    return;
  }
  idx -= 90112;
  if (idx < 196608) { wihw[idx] = f2bf(Wih[idx]); return; }
  idx -= 196608;
  if (idx < 196608) { whhw[idx] = f2bf(Whh[idx]); return; }
  idx -= 196608;
  if (idx < 32768) {
    wp2w[idx] = (idx < 33 * 256) ? f2bf(Wp2[idx]) : (short)0;
    return;
  }
  idx -= 32768;
  if (idx < 131072) {           // WPQK 512x256: [Wp1; Wq; Wk_h; 0]
    int r = idx >> 8, c = idx & 255;
    short v = 0;
    if (r < 256) v = f2bf(Wp1[r * 256 + c]);
    else if (r < 320) v = f2bf(Wq[(r - 256) * 256 + c]);
    else if (r < 384) v = f2bf(Wk[(size_t)(r - 320) * 261 + c]);
    wpqk[idx] = v;
    return;
  }
  idx -= 131072;
  if (idx < 147456) {           // [Wg1 ; Wd1] : 512x288
    wgdw[idx] = (idx < 73728) ? f2bf(Wg1[idx]) : f2bf(Wd1[idx - 73728]);
    return;
  }
  idx -= 147456;
  if (idx < 65536) {            // WFW 128x512: r0 = [Wg2|0]; r1..27 = [0|Wd2]
    int r = idx >> 9, c = idx & 511;
    short v = 0;
    if (r == 0 && c < 256) v = f2bf(Wg2[c]);
    else if (r >= 1 && r < 28 && c >= 256) v = f2bf(Wd2[(r - 1) * 256 + (c - 256)]);
    wfw[idx] = v;
    return;
  }
  idx -= 65536;
  if (idx < 384) {
    bpqkb[idx] = (idx < 256) ? bp1[idx] : ((idx < 320) ? bq[idx - 256] : 0.f);
    return;
  }
  idx -= 384;
  if (idx < 512) { bgd[idx] = (idx < 256) ? bg1[idx] : bd1[idx - 256]; return; }
  idx -= 512;
  if (idx < 128)
    bf2v[idx] = (idx == 0) ? bg2[0] : ((idx < 28) ? bd2[idx - 1] : 0.f);
}

// ---------------------------------------------------------------------------
// GRU elementwise.
// ---------------------------------------------------------------------------
__global__ __launch_bounds__(256) void gru_kernel(
    const short* __restrict__ GI, const short* __restrict__ GH,
    const float* __restrict__ Hin, float* __restrict__ H,
    short* __restrict__ FUS) {
  int idx = blockIdx.x * 256 + threadIdx.x;
  int row = idx >> 6;
  int c = (idx & 63) * 4;
  const short4v gr = *(const short4v*)(GI + (size_t)row * 768 + c);
  const short4v gz = *(const short4v*)(GI + (size_t)row * 768 + 256 + c);
  const short4v gn = *(const short4v*)(GI + (size_t)row * 768 + 512 + c);
  const short4v hr = *(const short4v*)(GH + (size_t)row * 768 + c);
  const short4v hz = *(const short4v*)(GH + (size_t)row * 768 + 256 + c);
  const short4v hn = *(const short4v*)(GH + (size_t)row * 768 + 512 + c);
  const f32x4 hi = *(const f32x4*)(Hin + (size_t)row * 256 + c);
  f32x4 o;
  short4v ob;
#pragma unroll
  for (int p = 0; p < 4; ++p) {
    float r = sigmoidf_(bf2f(gr[p]) + bf2f(hr[p]));
    float z = sigmoidf_(bf2f(gz[p]) + bf2f(hz[p]));
    float n = tanhf(bf2f(gn[p]) + r * bf2f(hn[p]));
    float h = (1.f - z) * n + z * hi[p];
    o[p] = h;
    ob[p] = f2bf(h);
  }
  *(f32x4*)(H + (size_t)row * 256 + c) = o;
  *(short4v*)(FUS + (size_t)row * 288 + c) = ob;
}

// ---------------------------------------------------------------------------
// Per-row softmax over attack logits -> value_source -> sender_values (32).
// ---------------------------------------------------------------------------
__global__ __launch_bounds__(256) void sv_kernel(
    const float* __restrict__ logits, const float* __restrict__ Wv,
    const float* __restrict__ bv, float* __restrict__ SV) {
  const int wave = threadIdx.x >> 6;
  const int lane = threadIdx.x & 63;
  const int row = blockIdx.x * 4 + wave;
  __shared__ float vs_s[4][29];
  float v = (lane < 27) ? logits[(size_t)row * 33 + 6 + lane] : -INFINITY;
  float m = v;
#pragma unroll
  for (int off = 32; off; off >>= 1) m = fmaxf(m, __shfl_xor(m, off));
  float e = (lane < 27) ? __expf(v - m) : 0.f;
  float s = e;
#pragma unroll
  for (int off = 32; off; off >>= 1) s += __shfl_xor(s, off);
  if (lane < 27) vs_s[wave][lane] = e / s;
  if (lane == 27) vs_s[wave][27] = 1.f;
  if (lane == 28) vs_s[wave][28] = 1.f / s;   // top1 = max prob
  __syncthreads();
  if (lane < 32) {
    float acc = bv[lane];
    const float* w = Wv + lane * 29;
#pragma unroll
    for (int c = 0; c < 29; ++c) acc += w[c] * vs_s[wave][c];
    SV[(size_t)row * 32 + lane] = acc;
  }
}

// ---------------------------------------------------------------------------
// Attention v5: 2 blocks per b; grid (1024, 2), 256 thr (4 waves).
// half 0: i = 0..15 (4 iters); half 1: i = 16..27 (3 iters).
// r9: per-b shared data staged ONCE per block (was 7x across iq-blocks);
//     NO block barriers inside the i-loop — all inter-phase communication
//     is wave-internal LDS (DS pipe is in-order per wave; wave lockstep),
//     fenced with wave_barrier() to stop compiler reordering only.
// r8: top4 via 4 rounds of {16-lane shuffle-max, mask one via ballot+ctz};
//     message loop split across both 32-lane halves.
// kh staged d-major stride 29 -> score loop 2 lanes/bank (free).
// ---------------------------------------------------------------------------
__global__ __launch_bounds__(256) void attn3_kernel(
    const float* __restrict__ QK, const float* __restrict__ rel,
    const float* __restrict__ Wk, const float* __restrict__ bk,
    const float* __restrict__ SV, const float* __restrict__ null_key,
    const float* __restrict__ null_value, const float* __restrict__ ln_g,
    const float* __restrict__ ln_b, short* __restrict__ FUS) {
  const int b    = blockIdx.x;
  const int half = blockIdx.y;
  const int t = threadIdx.x;
  const int wave = t >> 6, lane = t & 63;
  const int nit   = half ? 3 : 4;
  const int ibase = half ? 16 : 0;

  __shared__ float kh_s[64 * 29];       // [d-major][j], stride 29
  __shared__ float sv_s[28 * 32];       // rows 0..26 = SV, row 27 = null_value
  __shared__ float wkr_s[320];
  __shared__ float bk_s[64], nk_s[64];
  __shared__ float lng_s[32], lnb_s[32];
  __shared__ float q_s[4][64];
  __shared__ float rel_s[4][136];
  __shared__ float qws[4][28];          // [0:20) qwkr h*5+r | [20:24) qbk | [24:28) qnull
  __shared__ float s_row[4][112];

  // ---- block stage, once per (b, half) ----
  for (int idx = t; idx < 27 * 64; idx += 256) {
    int r = idx >> 6, c = idx & 63;     // r = j, c = d-index
    kh_s[c * 29 + r] = QK[(size_t)(b * 27 + r) * 128 + 64 + c];
  }
  for (int idx = t; idx < 27 * 32; idx += 256)
    sv_s[idx] = SV[(size_t)b * 864 + idx];
  for (int idx = t; idx < 320; idx += 256) {
    int a = idx / 5, r = idx - a * 5;
    wkr_s[idx] = Wk[(size_t)a * 261 + 256 + r];
  }
  if (t < 64) bk_s[t] = bk[t];
  else if (t < 128) nk_s[t - 64] = null_key[t - 64];
  else if (t < 160) sv_s[27 * 32 + (t - 128)] = null_value[t - 128];
  else if (t < 192) { lng_s[t - 160] = ln_g[t - 160]; lnb_s[t - 160] = ln_b[t - 160]; }
  __syncthreads();

  for (int it = 0; it < nit; ++it) {
    const int i = ibase + it * 4 + wave;  // half0: 0..15; half1: 16..27 (27 invalid)
    const int iw = (i < 27) ? i : 26;     // clamped for safe reads

    // ---- per-wave stage: q row + rel row (wave-internal only) ----
    q_s[wave][lane] = QK[(size_t)(b * 27 + iw) * 128 + lane];
    for (int idx = lane; idx < 135; idx += 64)
      rel_s[wave][idx] = rel[(size_t)(b * 27 + iw) * 135 + idx];
    __builtin_amdgcn_wave_barrier();

    // ---- per-wave precompute: qwkr, qbk, qnull ----
    if (lane < 28) {
      float acc = 0.f;
      if (lane < 20) {
        const int h = lane / 5, r = lane - h * 5;
#pragma unroll
        for (int d = 0; d < 16; ++d)
          acc += q_s[wave][h * 16 + d] * wkr_s[(h * 16 + d) * 5 + r];
      } else if (lane < 24) {
        const int h = lane - 20;
#pragma unroll
        for (int d = 0; d < 16; ++d)
          acc += q_s[wave][h * 16 + d] * bk_s[h * 16 + d];
      } else {
        const int h = lane - 24;
#pragma unroll
        for (int d = 0; d < 16; ++d)
          acc += q_s[wave][h * 16 + d] * nk_s[h * 16 + d];
      }
      qws[wave][lane] = acc;
    }
    __builtin_amdgcn_wave_barrier();

    // ---- scores: 112 items (28 j x 4 h) per wave, 2 lane-passes ----
#pragma unroll
    for (int pass = 0; pass < 2; ++pass) {
      const int item = pass * 64 + lane;
      if (item < 112) {
        const int j = item >> 2, h = item & 3;
        float s;
        if (j < 27) {
          float acc = qws[wave][20 + h];
          const float* q  = &q_s[wave][h * 16];
          const float* kh = &kh_s[(h * 16) * 29 + j];
#pragma unroll
          for (int d = 0; d < 16; ++d) acc += q[d] * kh[d * 29];
          const float* rp = &rel_s[wave][j * 5];
          const float* qw = &qws[wave][h * 5];
#pragma unroll
          for (int r = 0; r < 5; ++r) acc += rp[r] * qw[r];
          s = acc * 0.25f;
          if (j == i) s = NEGV;
        } else {
          s = qws[wave][24 + h] * 0.25f;
        }
        s_row[wave][item] = s;
      }
    }
    __builtin_amdgcn_wave_barrier();

    // ---- top4 + masked softmax over 28 per (i,h): ALL 64 lanes ----
    // lane = g*16 + li; head g owns lanes [g*16, g*16+16); lane li holds
    // j = li and j = li + 16 (the latter -inf for j >= 28).
    {
      const int g = lane >> 4;
      const int li = lane & 15;
      const int j1 = li + 16;
      const float v0 = s_row[wave][li * 4 + g];
      const float v1 = (j1 < 28) ? s_row[wave][j1 * 4 + g] : -INFINITY;
      float w0 = v0, w1 = v1;
      float m0 = 0.f, thr = 0.f;
#pragma unroll
      for (int r = 0; r < 4; ++r) {
        float gm = fmaxf(w0, w1);
#pragma unroll
        for (int off = 8; off; off >>= 1) gm = fmaxf(gm, __shfl_xor(gm, off));
        if (r == 0) m0 = gm;
        thr = gm;
        // mask exactly one instance of gm within this 16-lane group
        const unsigned long long b0 = __ballot(w0 == gm);
        const unsigned long long b1 = __ballot(w1 == gm);
        const unsigned seg0 = (unsigned)(b0 >> (g * 16)) & 0xFFFFu;
        const unsigned seg1 = (unsigned)(b1 >> (g * 16)) & 0xFFFFu;
        if (seg0) { if (li == __builtin_ctz(seg0)) w0 = -INFINITY; }
        else      { if (li == __builtin_ctz(seg1)) w1 = -INFINITY; }
      }
      float e0 = (v0 >= thr) ? __expf(v0 - m0) : 0.f;
      float e1 = (j1 < 28 && v1 >= thr) ? __expf(v1 - m0) : 0.f;
      float s = e0 + e1;
#pragma unroll
      for (int off = 8; off; off >>= 1) s += __shfl_xor(s, off);
      const float inv = 1.f / s;
      s_row[wave][li * 4 + g] = e0 * inv;
      if (j1 < 28) s_row[wave][j1 * 4 + g] = e1 * inv;
    }
    __builtin_amdgcn_wave_barrier();

    // ---- messages + layernorm: ALL 64 lanes (j split across halves) ----
    {
      const int sl = lane & 31;
      const int h = sl >> 3;
      const int jbase = (lane >> 5) * 14;   // half0: j 0..13, half1: j 14..27
      const float* al = &s_row[wave][h];
      float acc = 0.f;
#pragma unroll
      for (int jj = 0; jj < 14; ++jj)
        acc += al[(jbase + jj) * 4] * sv_s[(jbase + jj) * 32 + sl];
      acc += __shfl_xor(acc, 32);           // full message in all lanes
      float sum = acc;
#pragma unroll
      for (int off = 16; off; off >>= 1) sum += __shfl_xor(sum, off);
      const float mu = sum * (1.f / 32.f);
      const float d = acc - mu;
      float sq = d * d;
#pragma unroll
      for (int off = 16; off; off >>= 1) sq += __shfl_xor(sq, off);
      const float rs = rsqrtf(sq * (1.f / 32.f) + 1e-5f);
      const float nv = d * rs * lng_s[sl] + lnb_s[sl];
      if (i < 27 && lane < 32)
        FUS[(size_t)(b * 27 + i) * 288 + 256 + sl] = f2bf(nv);
    }
    __builtin_amdgcn_wave_barrier();   // before next iter overwrites q_s/rel_s/s_row
  }
}

// ---------------------------------------------------------------------------
// Final fuse.
// ---------------------------------------------------------------------------
__global__ __launch_bounds__(256) void fuse_kernel(
    const float* __restrict__ GDf, const float* __restrict__ LOG,
    float* __restrict__ out) {
  int idx = blockIdx.x * 256 + threadIdx.x;   // over ROWS*33
  int row = idx / 33, c = idx - row * 33;
  float v = LOG[idx];
  if (c >= 6) {
    float gate = sigmoidf_(GDf[(size_t)row * 28]);
    v += 0.1f * gate * GDf[(size_t)row * 28 + (c - 5)];
  }
  out[idx] = v;
}

// ---------------------------------------------------------------------------
extern "C" void kernel_launch(void* const* d_in, const int* in_sizes, int n_in,
                              void* d_out, int out_size, void* d_ws, size_t ws_size,
                              hipStream_t stream) {
  const float* inputs = (const float*)d_in[0];
  const float* hidden = (const float*)d_in[1];
  const float* rel    = (const float*)d_in[2];
  const float* W1  = (const float*)d_in[3];  const float* b1  = (const float*)d_in[4];
  const float* Wih = (const float*)d_in[5];  const float* bih = (const float*)d_in[6];
  const float* Whh = (const float*)d_in[7];  const float* bhh = (const float*)d_in[8];
  const float* Wp1 = (const float*)d_in[9];  const float* bp1 = (const float*)d_in[10];
  const float* Wp2 = (const float*)d_in[11]; const float* bp2 = (const float*)d_in[12];
  const float* Wq  = (const float*)d_in[13]; const float* bq  = (const float*)d_in[14];
  const float* Wk  = (const float*)d_in[15]; const float* bk  = (const float*)d_in[16];
  const float* Wv  = (const float*)d_in[17]; const float* bv  = (const float*)d_in[18];
  const float* ln_g = (const float*)d_in[19]; const float* ln_b = (const float*)d_in[20];
  const float* Wg1 = (const float*)d_in[21]; const float* bg1 = (const float*)d_in[22];
  const float* Wg2 = (const float*)d_in[23]; const float* bg2 = (const float*)d_in[24];
  const float* Wd1 = (const float*)d_in[25]; const float* bd1 = (const float*)d_in[26];
  const float* Wd2 = (const float*)d_in[27]; const float* bd2 = (const float*)d_in[28];
  const float* null_key   = (const float*)d_in[29];
  const float* null_value = (const float*)d_in[30];

  // ---- workspace layout (time-multiplexed; overlap-audited r7) ----
  char* wsb = (char*)d_ws;
  short* GIB = (short*)(wsb + 0);                    // 27648x768 bf16 (42.5MB)
  short* GDB = (short*)(wsb + 0);                    // 27648x512 bf16 (28.3MB)
  short* XINB = (short*)(wsb + 42467328);            // 27648x352 bf16
  short* GHB  = (short*)(wsb + 42467328);            // 27648x768 bf16 (all of R1)
  float* LOG  = (float*)(wsb + 42467328);            // +0       : 3.65MB
  float* QKB  = (float*)(wsb + 42467328 + 4194304);  // +4MiB    : 14.16MB -> ends +18.35MB
  float* SVB  = (float*)(wsb + 42467328 + 18874368); // +18MiB   : 3.54MB  -> ends +22.4MB
  float* LOGD = (float*)(wsb + 42467328 + 23068672); // +22MiB   : 3.10MB  -> ends +26.2MB
  short* XB   = (short*)(wsb + 84934656);
  short* FUS  = (short*)(wsb + 84934656);
  short* HIDB = (short*)(wsb + 84934656 + 16777216);
  short* P1B  = (short*)(wsb + 84934656 + 16777216);
  // Weights (persistent)
  char* wb = wsb + 115867648;
  short* W1W   = (short*)(wb + 0);        // 256x352
  short* WIHW  = (short*)(wb + 180224);   // 768x256
  short* WHHW  = (short*)(wb + 573440);   // 768x256
  short* WP2W  = (short*)(wb + 966656);   // 128x256
  short* WPQK  = (short*)(wb + 1032192);  // 512x256
  short* WGDW  = (short*)(wb + 1294336);  // 512x288
  short* WFW   = (short*)(wb + 1589248);  // 128x512
  float* BPQKb = (float*)(wb + 1720320);  // 384
  float* BGD   = (float*)(wb + 1721856);  // 512
  float* BF2   = (float*)(wb + 1723904);  // 128

  float* out = (float*)d_out;
  float* H   = out + (size_t)ROWS * 33;   // h output region, fp32

  // 1. bf16 conversions / packing
  conv_acts<<<65664, 256, 0, stream>>>(inputs, hidden, XINB, HIDB);
  conv_w<<<3364, 256, 0, stream>>>(W1, Wih, Whh, Wp1, Wp2, Wq, Wk, Wg1, Wd1,
                                   Wg2, Wd2, bp1, bq, bg1, bd1, bg2, bd2,
                                   W1W, WIHW, WHHW, WP2W, WPQK, WGDW, WFW,
                                   BPQKb, BGD, BF2);
  // 2. X = relu(inputs @ W1^T + b1)
  gemm_mfma<1, 1><<<dim3(216, 2), 256, 0, stream>>>(XINB, 352, W1W, 352, b1, XB, 256, 256, 352);
  // 3. GI = X @ Wih^T + bih
  gemm_mfma<0, 1><<<dim3(216, 6), 256, 0, stream>>>(XB, 256, WIHW, 256, bih, GIB, 768, 768, 256);
  // 4. GH = hidden @ Whh^T + bhh
  gemm_mfma<0, 1><<<dim3(216, 6), 256, 0, stream>>>(HIDB, 256, WHHW, 256, bhh, GHB, 768, 768, 256);
  // 5. GRU -> H (fp32, d_out) + fusion[:,0:256] (bf16)
  gru_kernel<<<6912, 256, 0, stream>>>(GIB, GHB, hidden, H, FUS);
  // 6. [P1 | QK] = h @ [Wp1; Wq; Wk_h]^T + [bp1; bq; 0]
  gemm_pqk<<<dim3(216, 3), 256, 0, stream>>>(FUS, WPQK, BPQKb, P1B, QKB);
  // 7. logits = P1 @ Wp2^T + bp2
  gemm_mfma<0, 0><<<dim3(216, 1), 256, 0, stream>>>(P1B, 256, WP2W, 256, bp2, LOG, 33, 33, 256);
  // 8. sender values
  sv_kernel<<<6912, 256, 0, stream>>>(LOG, Wv, bv, SVB);
  // 9. attention v5 -> fusion[:,256:288]
  attn3_kernel<<<dim3(1024, 2), 256, 0, stream>>>(QKB, rel, Wk, bk, SVB, null_key,
                                                  null_value, ln_g, ln_b, FUS);
  // 10. [G1 | D1] = relu(fusion @ [Wg1; Wd1]^T + [bg1; bd1])
  gemm_mfma<1, 1><<<dim3(216, 4), 256, 0, stream>>>(FUS, 288, WGDW, 288, BGD, GDB, 512, 512, 288);
  // 11. GDf = GD @ WFW^T + [bg2; bd2]
  gemm_mfma<0, 0><<<dim3(216, 1), 256, 0, stream>>>(GDB, 512, WFW, 512, BF2, LOGD, 28, 28, 512);
  // 12. final fuse
  fuse_kernel<<<3564, 256, 0, stream>>>(LOGD, LOG, out);
}

// Round 4
// 415.777 us; speedup vs baseline: 1.0083x; 1.0083x over previous
//
#include <hip/hip_runtime.h>
#include <cstdint>
#include <cstddef>

#define ROWS 27648
#define NEGV (-1e10f)

typedef __attribute__((ext_vector_type(8))) short bf16x8;
typedef __attribute__((ext_vector_type(4))) short short4v;
typedef __attribute__((ext_vector_type(4))) float f32x4;

__device__ __forceinline__ float sigmoidf_(float x) { return 1.f / (1.f + __expf(-x)); }
__device__ __forceinline__ float bf2f(short s) {
  union { float f; unsigned u; } x; x.u = ((unsigned)(unsigned short)s) << 16; return x.f;
}
__device__ __forceinline__ short f2bf(float f) {   // RNE
  union { float f; unsigned u; } x; x.f = f;
  unsigned r = (x.u + 0x7fffu + ((x.u >> 16) & 1u)) >> 16;
  return (short)r;
}

// ---------------------------------------------------------------------------
// bf16 MFMA GEMM: C = act(A @ B^T + bias); 128x128 tile, BK=32, 256 thr.
// Grid: (216 row-tiles, n col-tiles): same-A-slab blocks are id-congruent
// mod 8 => same XCD L2.
// ---------------------------------------------------------------------------
#define GLDS(gp, lp) __builtin_amdgcn_global_load_lds( \
  (const __attribute__((address_space(1))) void*)(gp), \
  (__attribute__((address_space(3))) void*)(lp), 16, 0, 0)

template <int ACT, int BF16OUT>
__global__ __launch_bounds__(256) void gemm_mfma(
    const short* __restrict__ A, int lda,
    const short* __restrict__ B, int ldb,
    const float* __restrict__ bias,
    void* __restrict__ Cv, int ldc, int nstore, int K) {
  __shared__ short As[128 * 32];
  __shared__ short Bs[128 * 32];
  const int tid = threadIdx.x;
  const int wave = tid >> 6, lane = tid & 63;
  const int m0 = blockIdx.x * 128, n0 = blockIdx.y * 128;
  const int srow = lane >> 2, scol = (lane & 3) * 8;
  const int sr0 = wave * 32;
  const int wm = (wave >> 1) * 64, wn = (wave & 1) * 64;
  const int fr = lane & 15, fk = (lane >> 4) * 8;

  f32x4 acc[4][4] = {};

  const short* pA0 = A + (size_t)(m0 + sr0 + srow) * lda + scol;
  const short* pA1 = pA0 + 16 * lda;
  const short* pB0 = B + (size_t)(n0 + sr0 + srow) * ldb + scol;
  const short* pB1 = pB0 + 16 * ldb;
  short* lA0 = &As[sr0 * 32];
  short* lA1 = &As[(sr0 + 16) * 32];
  short* lB0 = &Bs[sr0 * 32];
  short* lB1 = &Bs[(sr0 + 16) * 32];

  for (int k0 = 0; k0 < K; k0 += 32) {
    GLDS(pA0 + k0, lA0);
    GLDS(pA1 + k0, lA1);
    GLDS(pB0 + k0, lB0);
    GLDS(pB1 + k0, lB1);
    __syncthreads();
    bf16x8 af[4], bfr[4];
#pragma unroll
    for (int t = 0; t < 4; ++t) {
      af[t]  = *(const bf16x8*)&As[(wm + t * 16 + fr) * 32 + fk];
      bfr[t] = *(const bf16x8*)&Bs[(wn + t * 16 + fr) * 32 + fk];
    }
#pragma unroll
    for (int i = 0; i < 4; ++i)
#pragma unroll
      for (int j = 0; j < 4; ++j)
        acc[i][j] = __builtin_amdgcn_mfma_f32_16x16x32_bf16(af[i], bfr[j], acc[i][j], 0, 0, 0);
    __syncthreads();
  }

  const int rbase = m0 + wm + (lane >> 4) * 4;
#pragma unroll
  for (int j = 0; j < 4; ++j) {
    const int col = n0 + wn + j * 16 + fr;
    if (col >= nstore) continue;
    const float bv = bias ? bias[col] : 0.f;
#pragma unroll
    for (int i = 0; i < 4; ++i)
#pragma unroll
      for (int r = 0; r < 4; ++r) {
        const int row = rbase + i * 16 + r;
        float v = acc[i][j][r] + bv;
        if (ACT) v = fmaxf(v, 0.f);
        if (BF16OUT) ((short*)Cv)[(size_t)row * ldc + col] = f2bf(v);
        else         ((float*)Cv)[(size_t)row * ldc + col] = v;
      }
  }
}

// ---------------------------------------------------------------------------
// Split-output GEMM for [P1 | QK].
// ---------------------------------------------------------------------------
__global__ __launch_bounds__(256) void gemm_pqk(
    const short* __restrict__ A, const short* __restrict__ B,
    const float* __restrict__ bias,
    short* __restrict__ P1, float* __restrict__ QK) {
  __shared__ short As[128 * 32];
  __shared__ short Bs[128 * 32];
  const int tid = threadIdx.x;
  const int wave = tid >> 6, lane = tid & 63;
  const int m0 = blockIdx.x * 128, n0 = blockIdx.y * 128;
  const int srow = lane >> 2, scol = (lane & 3) * 8;
  const int sr0 = wave * 32;
  const int wm = (wave >> 1) * 64, wn = (wave & 1) * 64;
  const int fr = lane & 15, fk = (lane >> 4) * 8;

  f32x4 acc[4][4] = {};
  const short* pA0 = A + (size_t)(m0 + sr0 + srow) * 288 + scol;
  const short* pA1 = pA0 + 16 * 288;
  const short* pB0 = B + (size_t)(n0 + sr0 + srow) * 256 + scol;
  const short* pB1 = pB0 + 16 * 256;
  short* lA0 = &As[sr0 * 32];
  short* lA1 = &As[(sr0 + 16) * 32];
  short* lB0 = &Bs[sr0 * 32];
  short* lB1 = &Bs[(sr0 + 16) * 32];

  for (int k0 = 0; k0 < 256; k0 += 32) {
    GLDS(pA0 + k0, lA0);
    GLDS(pA1 + k0, lA1);
    GLDS(pB0 + k0, lB0);
    GLDS(pB1 + k0, lB1);
    __syncthreads();
    bf16x8 af[4], bfr[4];
#pragma unroll
    for (int t = 0; t < 4; ++t) {
      af[t]  = *(const bf16x8*)&As[(wm + t * 16 + fr) * 32 + fk];
      bfr[t] = *(const bf16x8*)&Bs[(wn + t * 16 + fr) * 32 + fk];
    }
#pragma unroll
    for (int i = 0; i < 4; ++i)
#pragma unroll
      for (int j = 0; j < 4; ++j)
        acc[i][j] = __builtin_amdgcn_mfma_f32_16x16x32_bf16(af[i], bfr[j], acc[i][j], 0, 0, 0);
    __syncthreads();
  }

  const int rbase = m0 + wm + (lane >> 4) * 4;
#pragma unroll
  for (int j = 0; j < 4; ++j) {
    const int col = n0 + wn + j * 16 + fr;
    if (col >= 384) continue;
    const float bv = bias[col];
#pragma unroll
    for (int i = 0; i < 4; ++i)
#pragma unroll
      for (int r = 0; r < 4; ++r) {
        const int row = rbase + i * 16 + r;
        float v = acc[i][j][r] + bv;
        if (col < 256) {
          P1[(size_t)row * 256 + col] = f2bf(fmaxf(v, 0.f));
        } else {
          QK[(size_t)row * 128 + (col - 256)] = v;
        }
      }
  }
}

// ---------------------------------------------------------------------------
// Combined activation + weight conversion / packing (r10: one launch).
// ---------------------------------------------------------------------------
__global__ __launch_bounds__(256) void conv_all(
    const float* __restrict__ inputs, const float* __restrict__ hidden,
    const float* __restrict__ W1, const float* __restrict__ Wih,
    const float* __restrict__ Whh, const float* __restrict__ Wp1,
    const float* __restrict__ Wp2, const float* __restrict__ Wq,
    const float* __restrict__ Wk, const float* __restrict__ Wg1,
    const float* __restrict__ Wd1, const float* __restrict__ Wg2,
    const float* __restrict__ Wd2, const float* __restrict__ bp1,
    const float* __restrict__ bq, const float* __restrict__ bg1,
    const float* __restrict__ bd1, const float* __restrict__ bg2,
    const float* __restrict__ bd2,
    short* __restrict__ xin, short* __restrict__ hid,
    short* __restrict__ w1w, short* __restrict__ wihw, short* __restrict__ whhw,
    short* __restrict__ wp2w, short* __restrict__ wpqk, short* __restrict__ wgdw,
    short* __restrict__ wfw, float* __restrict__ bpqkb, float* __restrict__ bgd,
    float* __restrict__ bf2v) {
  const int NX = ROWS * 352;
  const int NH = ROWS * 256;
  int idx = blockIdx.x * 256 + threadIdx.x;
  if (idx < NX) {
    int row = idx / 352, c = idx - row * 352;
    xin[idx] = (c < 322) ? f2bf(inputs[row * 322 + c]) : (short)0;
    return;
  }
  idx -= NX;
  if (idx < NH) { hid[idx] = f2bf(hidden[idx]); return; }
  idx -= NH;
  if (idx < 90112) {
    int r = idx / 352, c = idx - r * 352;
    w1w[idx] = (c < 322) ? f2bf(W1[r * 322 + c]) : (short)0;
    return;
  }
  idx -= 90112;
  if (idx < 196608) { wihw[idx] = f2bf(Wih[idx]); return; }
  idx -= 196608;
  if (idx < 196608) { whhw[idx] = f2bf(Whh[idx]); return; }
  idx -= 196608;
  if (idx < 32768) {
    wp2w[idx] = (idx < 33 * 256) ? f2bf(Wp2[idx]) : (short)0;
    return;
  }
  idx -= 32768;
  if (idx < 131072) {           // WPQK 512x256: [Wp1; Wq; Wk_h; 0]
    int r = idx >> 8, c = idx & 255;
    short v = 0;
    if (r < 256) v = f2bf(Wp1[r * 256 + c]);
    else if (r < 320) v = f2bf(Wq[(r - 256) * 256 + c]);
    else if (r < 384) v = f2bf(Wk[(size_t)(r - 320) * 261 + c]);
    wpqk[idx] = v;
    return;
  }
  idx -= 131072;
  if (idx < 147456) {           // [Wg1 ; Wd1] : 512x288
    wgdw[idx] = (idx < 73728) ? f2bf(Wg1[idx]) : f2bf(Wd1[idx - 73728]);
    return;
  }
  idx -= 147456;
  if (idx < 65536) {            // WFW 128x512: r0 = [Wg2|0]; r1..27 = [0|Wd2]
    int r = idx >> 9, c = idx & 511;
    short v = 0;
    if (r == 0 && c < 256) v = f2bf(Wg2[c]);
    else if (r >= 1 && r < 28 && c >= 256) v = f2bf(Wd2[(r - 1) * 256 + (c - 256)]);
    wfw[idx] = v;
    return;
  }
  idx -= 65536;
  if (idx < 384) {
    bpqkb[idx] = (idx < 256) ? bp1[idx] : ((idx < 320) ? bq[idx - 256] : 0.f);
    return;
  }
  idx -= 384;
  if (idx < 512) { bgd[idx] = (idx < 256) ? bg1[idx] : bd1[idx - 256]; return; }
  idx -= 512;
  if (idx < 128)
    bf2v[idx] = (idx == 0) ? bg2[0] : ((idx < 28) ? bd2[idx - 1] : 0.f);
}

// ---------------------------------------------------------------------------
// GRU elementwise.
// ---------------------------------------------------------------------------
__global__ __launch_bounds__(256) void gru_kernel(
    const short* __restrict__ GI, const short* __restrict__ GH,
    const float* __restrict__ Hin, float* __restrict__ H,
    short* __restrict__ FUS) {
  int idx = blockIdx.x * 256 + threadIdx.x;
  int row = idx >> 6;
  int c = (idx & 63) * 4;
  const short4v gr = *(const short4v*)(GI + (size_t)row * 768 + c);
  const short4v gz = *(const short4v*)(GI + (size_t)row * 768 + 256 + c);
  const short4v gn = *(const short4v*)(GI + (size_t)row * 768 + 512 + c);
  const short4v hr = *(const short4v*)(GH + (size_t)row * 768 + c);
  const short4v hz = *(const short4v*)(GH + (size_t)row * 768 + 256 + c);
  const short4v hn = *(const short4v*)(GH + (size_t)row * 768 + 512 + c);
  const f32x4 hi = *(const f32x4*)(Hin + (size_t)row * 256 + c);
  f32x4 o;
  short4v ob;
#pragma unroll
  for (int p = 0; p < 4; ++p) {
    float r = sigmoidf_(bf2f(gr[p]) + bf2f(hr[p]));
    float z = sigmoidf_(bf2f(gz[p]) + bf2f(hz[p]));
    float n = tanhf(bf2f(gn[p]) + r * bf2f(hn[p]));
    float h = (1.f - z) * n + z * hi[p];
    o[p] = h;
    ob[p] = f2bf(h);
  }
  *(f32x4*)(H + (size_t)row * 256 + c) = o;
  *(short4v*)(FUS + (size_t)row * 288 + c) = ob;
}

// ---------------------------------------------------------------------------
// Per-row softmax over attack logits -> value_source -> sender_values (32).
// ---------------------------------------------------------------------------
__global__ __launch_bounds__(256) void sv_kernel(
    const float* __restrict__ logits, const float* __restrict__ Wv,
    const float* __restrict__ bv, float* __restrict__ SV) {
  const int wave = threadIdx.x >> 6;
  const int lane = threadIdx.x & 63;
  const int row = blockIdx.x * 4 + wave;
  __shared__ float vs_s[4][29];
  float v = (lane < 27) ? logits[(size_t)row * 33 + 6 + lane] : -INFINITY;
  float m = v;
#pragma unroll
  for (int off = 32; off; off >>= 1) m = fmaxf(m, __shfl_xor(m, off));
  float e = (lane < 27) ? __expf(v - m) : 0.f;
  float s = e;
#pragma unroll
  for (int off = 32; off; off >>= 1) s += __shfl_xor(s, off);
  if (lane < 27) vs_s[wave][lane] = e / s;
  if (lane == 27) vs_s[wave][27] = 1.f;
  if (lane == 28) vs_s[wave][28] = 1.f / s;   // top1 = max prob
  __syncthreads();
  if (lane < 32) {
    float acc = bv[lane];
    const float* w = Wv + lane * 29;
#pragma unroll
    for (int c = 0; c < 29; ++c) acc += w[c] * vs_s[wave][c];
    SV[(size_t)row * 32 + lane] = acc;
  }
}

// ---------------------------------------------------------------------------
// Attention v6 (r10): one WAVE per (b,i); grid (1024, 7)  [r8 TLP]
// + wave_barrier() instead of __syncthreads for all post-stage phases
//   [r9-validated mechanism: DS ops are in-order per wave; the fence only
//    stops compiler reordering]. Single block barrier after the stage.
// top4 via 4 rounds of {16-lane shuffle-max, mask one via ballot+ctz};
// message loop split across both 32-lane halves (null_value = sv_s row 27).
// kh staged d-major stride 29 -> score loop 2 lanes/bank (free).
// ---------------------------------------------------------------------------
__global__ __launch_bounds__(256) void attn4_kernel(
    const float* __restrict__ QK, const float* __restrict__ rel,
    const float* __restrict__ Wk, const float* __restrict__ bk,
    const float* __restrict__ SV, const float* __restrict__ null_key,
    const float* __restrict__ null_value, const float* __restrict__ ln_g,
    const float* __restrict__ ln_b, short* __restrict__ FUS) {
  const int b  = blockIdx.x;
  const int iq = blockIdx.y;
  const int t = threadIdx.x;
  const int wave = t >> 6, lane = t & 63;
  const int i = iq * 4 + wave;          // 0..27 (27 invalid)
  const int iw = (i < 27) ? i : 26;     // clamped for safe reads

  __shared__ float kh_s[64 * 29];       // [d-major][j], stride 29
  __shared__ float sv_s[28 * 32];       // rows 0..26 = SV, row 27 = null_value
  __shared__ float q_s[4][64];
  __shared__ float wkr_s[320];
  __shared__ float bk_s[64], nk_s[64];
  __shared__ float lng_s[32], lnb_s[32];
  __shared__ float rel_s[4][136];
  __shared__ float qws[4][28];          // [0:20) qwkr h*5+r | [20:24) qbk | [24:28) qnull
  __shared__ float s_row[4][112];

  // ---- block stage (all loops safe for blockDim=256) ----
  for (int idx = t; idx < 27 * 64; idx += 256) {
    int r = idx >> 6, c = idx & 63;     // r = j, c = d-index
    kh_s[c * 29 + r] = QK[(size_t)(b * 27 + r) * 128 + 64 + c];
  }
  for (int idx = t; idx < 27 * 32; idx += 256)
    sv_s[idx] = SV[(size_t)b * 864 + idx];
  q_s[wave][lane] = QK[(size_t)(b * 27 + iw) * 128 + lane];
  for (int idx = t; idx < 320; idx += 256) {
    int a = idx / 5, r = idx - a * 5;
    wkr_s[idx] = Wk[(size_t)a * 261 + 256 + r];
  }
  if (t < 64) bk_s[t] = bk[t];
  else if (t < 128) nk_s[t - 64] = null_key[t - 64];
  else if (t < 160) sv_s[27 * 32 + (t - 128)] = null_value[t - 128];
  else if (t < 192) { lng_s[t - 160] = ln_g[t - 160]; lnb_s[t - 160] = ln_b[t - 160]; }
  for (int idx = lane; idx < 135; idx += 64)
    rel_s[wave][idx] = rel[(size_t)(b * 27 + iw) * 135 + idx];
  __syncthreads();   // only cross-wave barrier: kh_s/sv_s/wkr_s/bk/nk/ln shared

  // ---- per-wave precompute: qwkr, qbk, qnull ----
  if (lane < 28) {
    float acc = 0.f;
    if (lane < 20) {
      const int h = lane / 5, r = lane - h * 5;
#pragma unroll
      for (int d = 0; d < 16; ++d)
        acc += q_s[wave][h * 16 + d] * wkr_s[(h * 16 + d) * 5 + r];
    } else if (lane < 24) {
      const int h = lane - 20;
#pragma unroll
      for (int d = 0; d < 16; ++d)
        acc += q_s[wave][h * 16 + d] * bk_s[h * 16 + d];
    } else {
      const int h = lane - 24;
#pragma unroll
      for (int d = 0; d < 16; ++d)
        acc += q_s[wave][h * 16 + d] * nk_s[h * 16 + d];
    }
    qws[wave][lane] = acc;
  }
  __builtin_amdgcn_wave_barrier();   // qws: wave-internal LDS (DS in-order)

  // ---- scores: 112 items (28 j x 4 h) per wave, 2 lane-passes ----
#pragma unroll
  for (int pass = 0; pass < 2; ++pass) {
    const int item = pass * 64 + lane;
    if (item < 112) {
      const int j = item >> 2, h = item & 3;
      float s;
      if (j < 27) {
        float acc = qws[wave][20 + h];
        const float* q  = &q_s[wave][h * 16];
        const float* kh = &kh_s[(h * 16) * 29 + j];
#pragma unroll
        for (int d = 0; d < 16; ++d) acc += q[d] * kh[d * 29];
        const float* rp = &rel_s[wave][j * 5];
        const float* qw = &qws[wave][h * 5];
#pragma unroll
        for (int r = 0; r < 5; ++r) acc += rp[r] * qw[r];
        s = acc * 0.25f;
        if (j == i) s = NEGV;
      } else {
        s = qws[wave][24 + h] * 0.25f;
      }
      s_row[wave][item] = s;
    }
  }
  __builtin_amdgcn_wave_barrier();

  // ---- top4 + masked softmax over 28 per (i,h): ALL 64 lanes ----
  // lane = g*16 + li; head g owns lanes [g*16, g*16+16); lane li holds
  // j = li and j = li + 16 (the latter -inf for j >= 28).
  {
    const int g = lane >> 4;
    const int li = lane & 15;
    const int j1 = li + 16;
    const float v0 = s_row[wave][li * 4 + g];
    const float v1 = (j1 < 28) ? s_row[wave][j1 * 4 + g] : -INFINITY;
    float w0 = v0, w1 = v1;
    float m0 = 0.f, thr = 0.f;
#pragma unroll
    for (int r = 0; r < 4; ++r) {
      float gm = fmaxf(w0, w1);
#pragma unroll
      for (int off = 8; off; off >>= 1) gm = fmaxf(gm, __shfl_xor(gm, off));
      if (r == 0) m0 = gm;
      thr = gm;
      // mask exactly one instance of gm within this 16-lane group
      const unsigned long long b0 = __ballot(w0 == gm);
      const unsigned long long b1 = __ballot(w1 == gm);
      const unsigned seg0 = (unsigned)(b0 >> (g * 16)) & 0xFFFFu;
      const unsigned seg1 = (unsigned)(b1 >> (g * 16)) & 0xFFFFu;
      if (seg0) { if (li == __builtin_ctz(seg0)) w0 = -INFINITY; }
      else      { if (li == __builtin_ctz(seg1)) w1 = -INFINITY; }
    }
    float e0 = (v0 >= thr) ? __expf(v0 - m0) : 0.f;
    float e1 = (j1 < 28 && v1 >= thr) ? __expf(v1 - m0) : 0.f;
    float s = e0 + e1;
#pragma unroll
    for (int off = 8; off; off >>= 1) s += __shfl_xor(s, off);
    const float inv = 1.f / s;
    s_row[wave][li * 4 + g] = e0 * inv;
    if (j1 < 28) s_row[wave][j1 * 4 + g] = e1 * inv;
  }
  __builtin_amdgcn_wave_barrier();

  // ---- messages + layernorm: ALL 64 lanes (j split across halves) ----
  {
    const int sl = lane & 31;
    const int h = sl >> 3;
    const int jbase = (lane >> 5) * 14;   // half0: j 0..13, half1: j 14..27
    const float* al = &s_row[wave][h];
    float acc = 0.f;
#pragma unroll
    for (int jj = 0; jj < 14; ++jj)
      acc += al[(jbase + jj) * 4] * sv_s[(jbase + jj) * 32 + sl];
    acc += __shfl_xor(acc, 32);           // full message in all lanes
    float sum = acc;
#pragma unroll
    for (int off = 16; off; off >>= 1) sum += __shfl_xor(sum, off);
    const float mu = sum * (1.f / 32.f);
    const float d = acc - mu;
    float sq = d * d;
#pragma unroll
    for (int off = 16; off; off >>= 1) sq += __shfl_xor(sq, off);
    const float rs = rsqrtf(sq * (1.f / 32.f) + 1e-5f);
    const float nv = d * rs * lng_s[sl] + lnb_s[sl];
    if (i < 27 && lane < 32)
      FUS[(size_t)(b * 27 + i) * 288 + 256 + sl] = f2bf(nv);
  }
}

// ---------------------------------------------------------------------------
// Final fuse.
// ---------------------------------------------------------------------------
__global__ __launch_bounds__(256) void fuse_kernel(
    const float* __restrict__ GDf, const float* __restrict__ LOG,
    float* __restrict__ out) {
  int idx = blockIdx.x * 256 + threadIdx.x;   // over ROWS*33
  int row = idx / 33, c = idx - row * 33;
  float v = LOG[idx];
  if (c >= 6) {
    float gate = sigmoidf_(GDf[(size_t)row * 28]);
    v += 0.1f * gate * GDf[(size_t)row * 28 + (c - 5)];
  }
  out[idx] = v;
}

// ---------------------------------------------------------------------------
extern "C" void kernel_launch(void* const* d_in, const int* in_sizes, int n_in,
                              void* d_out, int out_size, void* d_ws, size_t ws_size,
                              hipStream_t stream) {
  const float* inputs = (const float*)d_in[0];
  const float* hidden = (const float*)d_in[1];
  const float* rel    = (const float*)d_in[2];
  const float* W1  = (const float*)d_in[3];  const float* b1  = (const float*)d_in[4];
  const float* Wih = (const float*)d_in[5];  const float* bih = (const float*)d_in[6];
  const float* Whh = (const float*)d_in[7];  const float* bhh = (const float*)d_in[8];
  const float* Wp1 = (const float*)d_in[9];  const float* bp1 = (const float*)d_in[10];
  const float* Wp2 = (const float*)d_in[11]; const float* bp2 = (const float*)d_in[12];
  const float* Wq  = (const float*)d_in[13]; const float* bq  = (const float*)d_in[14];
  const float* Wk  = (const float*)d_in[15]; const float* bk  = (const float*)d_in[16];
  const float* Wv  = (const float*)d_in[17]; const float* bv  = (const float*)d_in[18];
  const float* ln_g = (const float*)d_in[19]; const float* ln_b = (const float*)d_in[20];
  const float* Wg1 = (const float*)d_in[21]; const float* bg1 = (const float*)d_in[22];
  const float* Wg2 = (const float*)d_in[23]; const float* bg2 = (const float*)d_in[24];
  const float* Wd1 = (const float*)d_in[25]; const float* bd1 = (const float*)d_in[26];
  const float* Wd2 = (const float*)d_in[27]; const float* bd2 = (const float*)d_in[28];
  const float* null_key   = (const float*)d_in[29];
  const float* null_value = (const float*)d_in[30];

  // ---- workspace layout (time-multiplexed; overlap-audited r7) ----
  char* wsb = (char*)d_ws;
  short* GIB = (short*)(wsb + 0);                    // 27648x768 bf16 (42.5MB)
  short* GDB = (short*)(wsb + 0);                    // 27648x512 bf16 (28.3MB)
  short* XINB = (short*)(wsb + 42467328);            // 27648x352 bf16
  short* GHB  = (short*)(wsb + 42467328);            // 27648x768 bf16 (all of R1)
  float* LOG  = (float*)(wsb + 42467328);            // +0       : 3.65MB
  float* QKB  = (float*)(wsb + 42467328 + 4194304);  // +4MiB    : 14.16MB -> ends +18.35MB
  float* SVB  = (float*)(wsb + 42467328 + 18874368); // +18MiB   : 3.54MB  -> ends +22.4MB
  float* LOGD = (float*)(wsb + 42467328 + 23068672); // +22MiB   : 3.10MB  -> ends +26.2MB
  short* XB   = (short*)(wsb + 84934656);
  short* FUS  = (short*)(wsb + 84934656);
  short* HIDB = (short*)(wsb + 84934656 + 16777216);
  short* P1B  = (short*)(wsb + 84934656 + 16777216);
  // Weights (persistent)
  char* wb = wsb + 115867648;
  short* W1W   = (short*)(wb + 0);        // 256x352
  short* WIHW  = (short*)(wb + 180224);   // 768x256
  short* WHHW  = (short*)(wb + 573440);   // 768x256
  short* WP2W  = (short*)(wb + 966656);   // 128x256
  short* WPQK  = (short*)(wb + 1032192);  // 512x256
  short* WGDW  = (short*)(wb + 1294336);  // 512x288
  short* WFW   = (short*)(wb + 1589248);  // 128x512
  float* BPQKb = (float*)(wb + 1720320);  // 384
  float* BGD   = (float*)(wb + 1721856);  // 512
  float* BF2   = (float*)(wb + 1723904);  // 128

  float* out = (float*)d_out;
  float* H   = out + (size_t)ROWS * 33;   // h output region, fp32

  // 1. bf16 conversions / packing (acts + weights, one launch)
  conv_all<<<69028, 256, 0, stream>>>(inputs, hidden,
                                      W1, Wih, Whh, Wp1, Wp2, Wq, Wk, Wg1, Wd1,
                                      Wg2, Wd2, bp1, bq, bg1, bd1, bg2, bd2,
                                      XINB, HIDB,
                                      W1W, WIHW, WHHW, WP2W, WPQK, WGDW, WFW,
                                      BPQKb, BGD, BF2);
  // 2. X = relu(inputs @ W1^T + b1)
  gemm_mfma<1, 1><<<dim3(216, 2), 256, 0, stream>>>(XINB, 352, W1W, 352, b1, XB, 256, 256, 352);
  // 3. GI = X @ Wih^T + bih
  gemm_mfma<0, 1><<<dim3(216, 6), 256, 0, stream>>>(XB, 256, WIHW, 256, bih, GIB, 768, 768, 256);
  // 4. GH = hidden @ Whh^T + bhh
  gemm_mfma<0, 1><<<dim3(216, 6), 256, 0, stream>>>(HIDB, 256, WHHW, 256, bhh, GHB, 768, 768, 256);
  // 5. GRU -> H (fp32, d_out) + fusion[:,0:256] (bf16)
  gru_kernel<<<6912, 256, 0, stream>>>(GIB, GHB, hidden, H, FUS);
  // 6. [P1 | QK] = h @ [Wp1; Wq; Wk_h]^T + [bp1; bq; 0]
  gemm_pqk<<<dim3(216, 3), 256, 0, stream>>>(FUS, WPQK, BPQKb, P1B, QKB);
  // 7. logits = P1 @ Wp2^T + bp2
  gemm_mfma<0, 0><<<dim3(216, 1), 256, 0, stream>>>(P1B, 256, WP2W, 256, bp2, LOG, 33, 33, 256);
  // 8. sender values
  sv_kernel<<<6912, 256, 0, stream>>>(LOG, Wv, bv, SVB);
  // 9. attention v6 -> fusion[:,256:288]
  attn4_kernel<<<dim3(1024, 7), 256, 0, stream>>>(QKB, rel, Wk, bk, SVB, null_key,
                                                  null_value, ln_g, ln_b, FUS);
  // 10. [G1 | D1] = relu(fusion @ [Wg1; Wd1]^T + [bg1; bd1])
  gemm_mfma<1, 1><<<dim3(216, 4), 256, 0, stream>>>(FUS, 288, WGDW, 288, BGD, GDB, 512, 512, 288);
  // 11. GDf = GD @ WFW^T + [bg2; bd2]
  gemm_mfma<0, 0><<<dim3(216, 1), 256, 0, stream>>>(GDB, 512, WFW, 512, BF2, LOGD, 28, 28, 512);
  // 12. final fuse
  fuse_kernel<<<3564, 256, 0, stream>>>(LOGD, LOG, out);
}

// Round 5
// 404.450 us; speedup vs baseline: 1.0365x; 1.0280x over previous
//
#include <hip/hip_runtime.h>
#include <cstdint>
#include <cstddef>

#define ROWS 27648
#define NEGV (-1e10f)

typedef __attribute__((ext_vector_type(8))) short bf16x8;
typedef __attribute__((ext_vector_type(4))) short short4v;
typedef __attribute__((ext_vector_type(4))) float f32x4;

__device__ __forceinline__ float sigmoidf_(float x) { return 1.f / (1.f + __expf(-x)); }
__device__ __forceinline__ float bf2f(short s) {
  union { float f; unsigned u; } x; x.u = ((unsigned)(unsigned short)s) << 16; return x.f;
}
__device__ __forceinline__ short f2bf(float f) {   // RNE
  union { float f; unsigned u; } x; x.f = f;
  unsigned r = (x.u + 0x7fffu + ((x.u >> 16) & 1u)) >> 16;
  return (short)r;
}

// ---------------------------------------------------------------------------
// bf16 MFMA GEMM r11: BK=64 (half the barriers of BK=32), swizzled LDS.
// [128][64] LDS tile; GLDS dest is linear (HW: wave-base + lane*16), so the
// swizzle is applied on the GLOBAL source chunk (scol = ((lane&7)^srow)*8)
// and on the fragment-read index (idx ^ ((row&7)<<3)) — rule "both sides or
// neither". K%64==32 handled by a 32-wide tail in a separate linear buffer.
// Grid: (216 row-tiles, n col-tiles): same-A-slab blocks id-congruent mod 8
// => same XCD L2.
// ---------------------------------------------------------------------------
#define GLDS(gp, lp) __builtin_amdgcn_global_load_lds( \
  (const __attribute__((address_space(1))) void*)(gp), \
  (__attribute__((address_space(3))) void*)(lp), 16, 0, 0)

template <int ACT, int BF16OUT>
__global__ __launch_bounds__(256) void gemm_mfma(
    const short* __restrict__ A, int lda,
    const short* __restrict__ B, int ldb,
    const float* __restrict__ bias,
    void* __restrict__ Cv, int ldc, int nstore, int K) {
  extern __shared__ short smem[];
  short* As = smem;              // [128][64] swizzled, 16 KB
  short* Bs = smem + 8192;       // [128][64] swizzled, 16 KB
  const int tid = threadIdx.x;
  const int wave = tid >> 6, lane = tid & 63;
  const int m0 = blockIdx.x * 128, n0 = blockIdx.y * 128;
  const int srow = lane >> 3;                    // 0..7 within 8-row GLDS group
  const int scol = ((lane & 7) ^ srow) * 8;      // swizzled 16B chunk (shorts)
  const int sr0 = wave * 32;
  const int wm = (wave >> 1) * 64, wn = (wave & 1) * 64;
  const int fr = lane & 15, fk = (lane >> 4) * 8;

  f32x4 acc[4][4] = {};

  const short* pA = A + (size_t)(m0 + sr0 + srow) * lda + scol;
  const short* pB = B + (size_t)(n0 + sr0 + srow) * ldb + scol;
  short* lA = &As[sr0 * 64];
  short* lB = &Bs[sr0 * 64];

  const int KB = K & ~63;
  for (int k0 = 0; k0 < KB; k0 += 64) {
#pragma unroll
    for (int g = 0; g < 4; ++g) {
      GLDS(pA + k0 + g * 8 * lda, lA + g * 512);
      GLDS(pB + k0 + g * 8 * ldb, lB + g * 512);
    }
    __syncthreads();
#pragma unroll
    for (int ks = 0; ks < 2; ++ks) {
      bf16x8 af[4], bfr[4];
#pragma unroll
      for (int t = 0; t < 4; ++t) {
        const int ra = wm + t * 16 + fr;
        const int rb = wn + t * 16 + fr;
        af[t]  = *(const bf16x8*)&As[(ra * 64 + ks * 32 + fk) ^ ((ra & 7) << 3)];
        bfr[t] = *(const bf16x8*)&Bs[(rb * 64 + ks * 32 + fk) ^ ((rb & 7) << 3)];
      }
#pragma unroll
      for (int i = 0; i < 4; ++i)
#pragma unroll
        for (int j = 0; j < 4; ++j)
          acc[i][j] = __builtin_amdgcn_mfma_f32_16x16x32_bf16(af[i], bfr[j], acc[i][j], 0, 0, 0);
    }
    __syncthreads();
  }

  if (K & 32) {                  // 32-wide tail: separate linear buffers
    short* As2 = smem + 16384;   // [128][32], 8 KB
    short* Bs2 = smem + 20480;   // [128][32], 8 KB
    const int sr2 = lane >> 2, sc2 = (lane & 3) * 8;
    const short* qA = A + (size_t)(m0 + sr0 + sr2) * lda + sc2 + KB;
    const short* qB = B + (size_t)(n0 + sr0 + sr2) * ldb + sc2 + KB;
    GLDS(qA, &As2[sr0 * 32]);
    GLDS(qA + 16 * lda, &As2[(sr0 + 16) * 32]);
    GLDS(qB, &Bs2[sr0 * 32]);
    GLDS(qB + 16 * ldb, &Bs2[(sr0 + 16) * 32]);
    __syncthreads();
    bf16x8 af[4], bfr[4];
#pragma unroll
    for (int t = 0; t < 4; ++t) {
      af[t]  = *(const bf16x8*)&As2[(wm + t * 16 + fr) * 32 + fk];
      bfr[t] = *(const bf16x8*)&Bs2[(wn + t * 16 + fr) * 32 + fk];
    }
#pragma unroll
    for (int i = 0; i < 4; ++i)
#pragma unroll
      for (int j = 0; j < 4; ++j)
        acc[i][j] = __builtin_amdgcn_mfma_f32_16x16x32_bf16(af[i], bfr[j], acc[i][j], 0, 0, 0);
  }

  const int rbase = m0 + wm + (lane >> 4) * 4;
#pragma unroll
  for (int j = 0; j < 4; ++j) {
    const int col = n0 + wn + j * 16 + fr;
    if (col >= nstore) continue;
    const float bv = bias ? bias[col] : 0.f;
#pragma unroll
    for (int i = 0; i < 4; ++i)
#pragma unroll
      for (int r = 0; r < 4; ++r) {
        const int row = rbase + i * 16 + r;
        float v = acc[i][j][r] + bv;
        if (ACT) v = fmaxf(v, 0.f);
        if (BF16OUT) ((short*)Cv)[(size_t)row * ldc + col] = f2bf(v);
        else         ((float*)Cv)[(size_t)row * ldc + col] = v;
      }
  }
}

// ---------------------------------------------------------------------------
// Split-output GEMM for [P1 | QK] (r11: BK=64 swizzled, K=256, no tail).
// ---------------------------------------------------------------------------
__global__ __launch_bounds__(256) void gemm_pqk(
    const short* __restrict__ A, const short* __restrict__ B,
    const float* __restrict__ bias,
    short* __restrict__ P1, float* __restrict__ QK) {
  extern __shared__ short smem[];
  short* As = smem;
  short* Bs = smem + 8192;
  const int tid = threadIdx.x;
  const int wave = tid >> 6, lane = tid & 63;
  const int m0 = blockIdx.x * 128, n0 = blockIdx.y * 128;
  const int srow = lane >> 3;
  const int scol = ((lane & 7) ^ srow) * 8;
  const int sr0 = wave * 32;
  const int wm = (wave >> 1) * 64, wn = (wave & 1) * 64;
  const int fr = lane & 15, fk = (lane >> 4) * 8;

  f32x4 acc[4][4] = {};
  const short* pA = A + (size_t)(m0 + sr0 + srow) * 288 + scol;
  const short* pB = B + (size_t)(n0 + sr0 + srow) * 256 + scol;
  short* lA = &As[sr0 * 64];
  short* lB = &Bs[sr0 * 64];

  for (int k0 = 0; k0 < 256; k0 += 64) {
#pragma unroll
    for (int g = 0; g < 4; ++g) {
      GLDS(pA + k0 + g * 8 * 288, lA + g * 512);
      GLDS(pB + k0 + g * 8 * 256, lB + g * 512);
    }
    __syncthreads();
#pragma unroll
    for (int ks = 0; ks < 2; ++ks) {
      bf16x8 af[4], bfr[4];
#pragma unroll
      for (int t = 0; t < 4; ++t) {
        const int ra = wm + t * 16 + fr;
        const int rb = wn + t * 16 + fr;
        af[t]  = *(const bf16x8*)&As[(ra * 64 + ks * 32 + fk) ^ ((ra & 7) << 3)];
        bfr[t] = *(const bf16x8*)&Bs[(rb * 64 + ks * 32 + fk) ^ ((rb & 7) << 3)];
      }
#pragma unroll
      for (int i = 0; i < 4; ++i)
#pragma unroll
        for (int j = 0; j < 4; ++j)
          acc[i][j] = __builtin_amdgcn_mfma_f32_16x16x32_bf16(af[i], bfr[j], acc[i][j], 0, 0, 0);
    }
    __syncthreads();
  }

  const int rbase = m0 + wm + (lane >> 4) * 4;
#pragma unroll
  for (int j = 0; j < 4; ++j) {
    const int col = n0 + wn + j * 16 + fr;
    if (col >= 384) continue;
    const float bv = bias[col];
#pragma unroll
    for (int i = 0; i < 4; ++i)
#pragma unroll
      for (int r = 0; r < 4; ++r) {
        const int row = rbase + i * 16 + r;
        float v = acc[i][j][r] + bv;
        if (col < 256) {
          P1[(size_t)row * 256 + col] = f2bf(fmaxf(v, 0.f));
        } else {
          QK[(size_t)row * 128 + (col - 256)] = v;
        }
      }
  }
}

// ---------------------------------------------------------------------------
// Combined activation + weight conversion / packing.
// ---------------------------------------------------------------------------
__global__ __launch_bounds__(256) void conv_all(
    const float* __restrict__ inputs, const float* __restrict__ hidden,
    const float* __restrict__ W1, const float* __restrict__ Wih,
    const float* __restrict__ Whh, const float* __restrict__ Wp1,
    const float* __restrict__ Wp2, const float* __restrict__ Wq,
    const float* __restrict__ Wk, const float* __restrict__ Wg1,
    const float* __restrict__ Wd1, const float* __restrict__ Wg2,
    const float* __restrict__ Wd2, const float* __restrict__ bp1,
    const float* __restrict__ bq, const float* __restrict__ bg1,
    const float* __restrict__ bd1, const float* __restrict__ bg2,
    const float* __restrict__ bd2,
    short* __restrict__ xin, short* __restrict__ hid,
    short* __restrict__ w1w, short* __restrict__ wihw, short* __restrict__ whhw,
    short* __restrict__ wp2w, short* __restrict__ wpqk, short* __restrict__ wgdw,
    short* __restrict__ wfw, float* __restrict__ bpqkb, float* __restrict__ bgd,
    float* __restrict__ bf2v) {
  const int NX = ROWS * 352;
  const int NH = ROWS * 256;
  int idx = blockIdx.x * 256 + threadIdx.x;
  if (idx < NX) {
    int row = idx / 352, c = idx - row * 352;
    xin[idx] = (c < 322) ? f2bf(inputs[row * 322 + c]) : (short)0;
    return;
  }
  idx -= NX;
  if (idx < NH) { hid[idx] = f2bf(hidden[idx]); return; }
  idx -= NH;
  if (idx < 90112) {
    int r = idx / 352, c = idx - r * 352;
    w1w[idx] = (c < 322) ? f2bf(W1[r * 322 + c]) : (short)0;
    return;
  }
  idx -= 90112;
  if (idx < 196608) { wihw[idx] = f2bf(Wih[idx]); return; }
  idx -= 196608;
  if (idx < 196608) { whhw[idx] = f2bf(Whh[idx]); return; }
  idx -= 196608;
  if (idx < 32768) {
    wp2w[idx] = (idx < 33 * 256) ? f2bf(Wp2[idx]) : (short)0;
    return;
  }
  idx -= 32768;
  if (idx < 131072) {           // WPQK 512x256: [Wp1; Wq; Wk_h; 0]
    int r = idx >> 8, c = idx & 255;
    short v = 0;
    if (r < 256) v = f2bf(Wp1[r * 256 + c]);
    else if (r < 320) v = f2bf(Wq[(r - 256) * 256 + c]);
    else if (r < 384) v = f2bf(Wk[(size_t)(r - 320) * 261 + c]);
    wpqk[idx] = v;
    return;
  }
  idx -= 131072;
  if (idx < 147456) {           // [Wg1 ; Wd1] : 512x288
    wgdw[idx] = (idx < 73728) ? f2bf(Wg1[idx]) : f2bf(Wd1[idx - 73728]);
    return;
  }
  idx -= 147456;
  if (idx < 65536) {            // WFW 128x512: r0 = [Wg2|0]; r1..27 = [0|Wd2]
    int r = idx >> 9, c = idx & 511;
    short v = 0;
    if (r == 0 && c < 256) v = f2bf(Wg2[c]);
    else if (r >= 1 && r < 28 && c >= 256) v = f2bf(Wd2[(r - 1) * 256 + (c - 256)]);
    wfw[idx] = v;
    return;
  }
  idx -= 65536;
  if (idx < 384) {
    bpqkb[idx] = (idx < 256) ? bp1[idx] : ((idx < 320) ? bq[idx - 256] : 0.f);
    return;
  }
  idx -= 384;
  if (idx < 512) { bgd[idx] = (idx < 256) ? bg1[idx] : bd1[idx - 256]; return; }
  idx -= 512;
  if (idx < 128)
    bf2v[idx] = (idx == 0) ? bg2[0] : ((idx < 28) ? bd2[idx - 1] : 0.f);
}

// ---------------------------------------------------------------------------
// GRU elementwise.
// ---------------------------------------------------------------------------
__global__ __launch_bounds__(256) void gru_kernel(
    const short* __restrict__ GI, const short* __restrict__ GH,
    const float* __restrict__ Hin, float* __restrict__ H,
    short* __restrict__ FUS) {
  int idx = blockIdx.x * 256 + threadIdx.x;
  int row = idx >> 6;
  int c = (idx & 63) * 4;
  const short4v gr = *(const short4v*)(GI + (size_t)row * 768 + c);
  const short4v gz = *(const short4v*)(GI + (size_t)row * 768 + 256 + c);
  const short4v gn = *(const short4v*)(GI + (size_t)row * 768 + 512 + c);
  const short4v hr = *(const short4v*)(GH + (size_t)row * 768 + c);
  const short4v hz = *(const short4v*)(GH + (size_t)row * 768 + 256 + c);
  const short4v hn = *(const short4v*)(GH + (size_t)row * 768 + 512 + c);
  const f32x4 hi = *(const f32x4*)(Hin + (size_t)row * 256 + c);
  f32x4 o;
  short4v ob;
#pragma unroll
  for (int p = 0; p < 4; ++p) {
    float r = sigmoidf_(bf2f(gr[p]) + bf2f(hr[p]));
    float z = sigmoidf_(bf2f(gz[p]) + bf2f(hz[p]));
    float n = tanhf(bf2f(gn[p]) + r * bf2f(hn[p]));
    float h = (1.f - z) * n + z * hi[p];
    o[p] = h;
    ob[p] = f2bf(h);
  }
  *(f32x4*)(H + (size_t)row * 256 + c) = o;
  *(short4v*)(FUS + (size_t)row * 288 + c) = ob;
}

// ---------------------------------------------------------------------------
// Per-row softmax over attack logits -> value_source -> sender_values (32).
// ---------------------------------------------------------------------------
__global__ __launch_bounds__(256) void sv_kernel(
    const float* __restrict__ logits, const float* __restrict__ Wv,
    const float* __restrict__ bv, float* __restrict__ SV) {
  const int wave = threadIdx.x >> 6;
  const int lane = threadIdx.x & 63;
  const int row = blockIdx.x * 4 + wave;
  __shared__ float vs_s[4][29];
  float v = (lane < 27) ? logits[(size_t)row * 33 + 6 + lane] : -INFINITY;
  float m = v;
#pragma unroll
  for (int off = 32; off; off >>= 1) m = fmaxf(m, __shfl_xor(m, off));
  float e = (lane < 27) ? __expf(v - m) : 0.f;
  float s = e;
#pragma unroll
  for (int off = 32; off; off >>= 1) s += __shfl_xor(s, off);
  if (lane < 27) vs_s[wave][lane] = e / s;
  if (lane == 27) vs_s[wave][27] = 1.f;
  if (lane == 28) vs_s[wave][28] = 1.f / s;   // top1 = max prob
  __syncthreads();
  if (lane < 32) {
    float acc = bv[lane];
    const float* w = Wv + lane * 29;
#pragma unroll
    for (int c = 0; c < 29; ++c) acc += w[c] * vs_s[wave][c];
    SV[(size_t)row * 32 + lane] = acc;
  }
}

// ---------------------------------------------------------------------------
// Attention v6 (kept from r10, verified): one WAVE per (b,i); grid (1024, 7);
// single block barrier after stage; wave-fences for wave-internal LDS phases;
// 64-lane top4 via ballot+ctz; messages split across halves.
// ---------------------------------------------------------------------------
__global__ __launch_bounds__(256) void attn4_kernel(
    const float* __restrict__ QK, const float* __restrict__ rel,
    const float* __restrict__ Wk, const float* __restrict__ bk,
    const float* __restrict__ SV, const float* __restrict__ null_key,
    const float* __restrict__ null_value, const float* __restrict__ ln_g,
    const float* __restrict__ ln_b, short* __restrict__ FUS) {
  const int b  = blockIdx.x;
  const int iq = blockIdx.y;
  const int t = threadIdx.x;
  const int wave = t >> 6, lane = t & 63;
  const int i = iq * 4 + wave;          // 0..27 (27 invalid)
  const int iw = (i < 27) ? i : 26;     // clamped for safe reads

  __shared__ float kh_s[64 * 29];       // [d-major][j], stride 29
  __shared__ float sv_s[28 * 32];       // rows 0..26 = SV, row 27 = null_value
  __shared__ float q_s[4][64];
  __shared__ float wkr_s[320];
  __shared__ float bk_s[64], nk_s[64];
  __shared__ float lng_s[32], lnb_s[32];
  __shared__ float rel_s[4][136];
  __shared__ float qws[4][28];          // [0:20) qwkr h*5+r | [20:24) qbk | [24:28) qnull
  __shared__ float s_row[4][112];

  // ---- block stage (all loops safe for blockDim=256) ----
  for (int idx = t; idx < 27 * 64; idx += 256) {
    int r = idx >> 6, c = idx & 63;     // r = j, c = d-index
    kh_s[c * 29 + r] = QK[(size_t)(b * 27 + r) * 128 + 64 + c];
  }
  for (int idx = t; idx < 27 * 32; idx += 256)
    sv_s[idx] = SV[(size_t)b * 864 + idx];
  q_s[wave][lane] = QK[(size_t)(b * 27 + iw) * 128 + lane];
  for (int idx = t; idx < 320; idx += 256) {
    int a = idx / 5, r = idx - a * 5;
    wkr_s[idx] = Wk[(size_t)a * 261 + 256 + r];
  }
  if (t < 64) bk_s[t] = bk[t];
  else if (t < 128) nk_s[t - 64] = null_key[t - 64];
  else if (t < 160) sv_s[27 * 32 + (t - 128)] = null_value[t - 128];
  else if (t < 192) { lng_s[t - 160] = ln_g[t - 160]; lnb_s[t - 160] = ln_b[t - 160]; }
  for (int idx = lane; idx < 135; idx += 64)
    rel_s[wave][idx] = rel[(size_t)(b * 27 + iw) * 135 + idx];
  __syncthreads();

  // ---- per-wave precompute: qwkr, qbk, qnull ----
  if (lane < 28) {
    float acc = 0.f;
    if (lane < 20) {
      const int h = lane / 5, r = lane - h * 5;
#pragma unroll
      for (int d = 0; d < 16; ++d)
        acc += q_s[wave][h * 16 + d] * wkr_s[(h * 16 + d) * 5 + r];
    } else if (lane < 24) {
      const int h = lane - 20;
#pragma unroll
      for (int d = 0; d < 16; ++d)
        acc += q_s[wave][h * 16 + d] * bk_s[h * 16 + d];
    } else {
      const int h = lane - 24;
#pragma unroll
      for (int d = 0; d < 16; ++d)
        acc += q_s[wave][h * 16 + d] * nk_s[h * 16 + d];
    }
    qws[wave][lane] = acc;
  }
  __builtin_amdgcn_wave_barrier();

  // ---- scores: 112 items (28 j x 4 h) per wave, 2 lane-passes ----
#pragma unroll
  for (int pass = 0; pass < 2; ++pass) {
    const int item = pass * 64 + lane;
    if (item < 112) {
      const int j = item >> 2, h = item & 3;
      float s;
      if (j < 27) {
        float acc = qws[wave][20 + h];
        const float* q  = &q_s[wave][h * 16];
        const float* kh = &kh_s[(h * 16) * 29 + j];
#pragma unroll
        for (int d = 0; d < 16; ++d) acc += q[d] * kh[d * 29];
        const float* rp = &rel_s[wave][j * 5];
        const float* qw = &qws[wave][h * 5];
#pragma unroll
        for (int r = 0; r < 5; ++r) acc += rp[r] * qw[r];
        s = acc * 0.25f;
        if (j == i) s = NEGV;
      } else {
        s = qws[wave][24 + h] * 0.25f;
      }
      s_row[wave][item] = s;
    }
  }
  __builtin_amdgcn_wave_barrier();

  // ---- top4 + masked softmax over 28 per (i,h): ALL 64 lanes ----
  {
    const int g = lane >> 4;
    const int li = lane & 15;
    const int j1 = li + 16;
    const float v0 = s_row[wave][li * 4 + g];
    const float v1 = (j1 < 28) ? s_row[wave][j1 * 4 + g] : -INFINITY;
    float w0 = v0, w1 = v1;
    float m0 = 0.f, thr = 0.f;
#pragma unroll
    for (int r = 0; r < 4; ++r) {
      float gm = fmaxf(w0, w1);
#pragma unroll
      for (int off = 8; off; off >>= 1) gm = fmaxf(gm, __shfl_xor(gm, off));
      if (r == 0) m0 = gm;
      thr = gm;
      const unsigned long long b0 = __ballot(w0 == gm);
      const unsigned long long b1 = __ballot(w1 == gm);
      const unsigned seg0 = (unsigned)(b0 >> (g * 16)) & 0xFFFFu;
      const unsigned seg1 = (unsigned)(b1 >> (g * 16)) & 0xFFFFu;
      if (seg0) { if (li == __builtin_ctz(seg0)) w0 = -INFINITY; }
      else      { if (li == __builtin_ctz(seg1)) w1 = -INFINITY; }
    }
    float e0 = (v0 >= thr) ? __expf(v0 - m0) : 0.f;
    float e1 = (j1 < 28 && v1 >= thr) ? __expf(v1 - m0) : 0.f;
    float s = e0 + e1;
#pragma unroll
    for (int off = 8; off; off >>= 1) s += __shfl_xor(s, off);
    const float inv = 1.f / s;
    s_row[wave][li * 4 + g] = e0 * inv;
    if (j1 < 28) s_row[wave][j1 * 4 + g] = e1 * inv;
  }
  __builtin_amdgcn_wave_barrier();

  // ---- messages + layernorm: ALL 64 lanes (j split across halves) ----
  {
    const int sl = lane & 31;
    const int h = sl >> 3;
    const int jbase = (lane >> 5) * 14;   // half0: j 0..13, half1: j 14..27
    const float* al = &s_row[wave][h];
    float acc = 0.f;
#pragma unroll
    for (int jj = 0; jj < 14; ++jj)
      acc += al[(jbase + jj) * 4] * sv_s[(jbase + jj) * 32 + sl];
    acc += __shfl_xor(acc, 32);           // full message in all lanes
    float sum = acc;
#pragma unroll
    for (int off = 16; off; off >>= 1) sum += __shfl_xor(sum, off);
    const float mu = sum * (1.f / 32.f);
    const float d = acc - mu;
    float sq = d * d;
#pragma unroll
    for (int off = 16; off; off >>= 1) sq += __shfl_xor(sq, off);
    const float rs = rsqrtf(sq * (1.f / 32.f) + 1e-5f);
    const float nv = d * rs * lng_s[sl] + lnb_s[sl];
    if (i < 27 && lane < 32)
      FUS[(size_t)(b * 27 + i) * 288 + 256 + sl] = f2bf(nv);
  }
}

// ---------------------------------------------------------------------------
// Final fuse.
// ---------------------------------------------------------------------------
__global__ __launch_bounds__(256) void fuse_kernel(
    const float* __restrict__ GDf, const float* __restrict__ LOG,
    float* __restrict__ out) {
  int idx = blockIdx.x * 256 + threadIdx.x;   // over ROWS*33
  int row = idx / 33, c = idx - row * 33;
  float v = LOG[idx];
  if (c >= 6) {
    float gate = sigmoidf_(GDf[(size_t)row * 28]);
    v += 0.1f * gate * GDf[(size_t)row * 28 + (c - 5)];
  }
  out[idx] = v;
}

// ---------------------------------------------------------------------------
extern "C" void kernel_launch(void* const* d_in, const int* in_sizes, int n_in,
                              void* d_out, int out_size, void* d_ws, size_t ws_size,
                              hipStream_t stream) {
  const float* inputs = (const float*)d_in[0];
  const float* hidden = (const float*)d_in[1];
  const float* rel    = (const float*)d_in[2];
  const float* W1  = (const float*)d_in[3];  const float* b1  = (const float*)d_in[4];
  const float* Wih = (const float*)d_in[5];  const float* bih = (const float*)d_in[6];
  const float* Whh = (const float*)d_in[7];  const float* bhh = (const float*)d_in[8];
  const float* Wp1 = (const float*)d_in[9];  const float* bp1 = (const float*)d_in[10];
  const float* Wp2 = (const float*)d_in[11]; const float* bp2 = (const float*)d_in[12];
  const float* Wq  = (const float*)d_in[13]; const float* bq  = (const float*)d_in[14];
  const float* Wk  = (const float*)d_in[15]; const float* bk  = (const float*)d_in[16];
  const float* Wv  = (const float*)d_in[17]; const float* bv  = (const float*)d_in[18];
  const float* ln_g = (const float*)d_in[19]; const float* ln_b = (const float*)d_in[20];
  const float* Wg1 = (const float*)d_in[21]; const float* bg1 = (const float*)d_in[22];
  const float* Wg2 = (const float*)d_in[23]; const float* bg2 = (const float*)d_in[24];
  const float* Wd1 = (const float*)d_in[25]; const float* bd1 = (const float*)d_in[26];
  const float* Wd2 = (const float*)d_in[27]; const float* bd2 = (const float*)d_in[28];
  const float* null_key   = (const float*)d_in[29];
  const float* null_value = (const float*)d_in[30];

  // ---- workspace layout (time-multiplexed; overlap-audited r7) ----
  char* wsb = (char*)d_ws;
  short* GIB = (short*)(wsb + 0);                    // 27648x768 bf16 (42.5MB)
  short* GDB = (short*)(wsb + 0);                    // 27648x512 bf16 (28.3MB)
  short* XINB = (short*)(wsb + 42467328);            // 27648x352 bf16
  short* GHB  = (short*)(wsb + 42467328);            // 27648x768 bf16 (all of R1)
  float* LOG  = (float*)(wsb + 42467328);            // +0       : 3.65MB
  float* QKB  = (float*)(wsb + 42467328 + 4194304);  // +4MiB    : 14.16MB -> ends +18.35MB
  float* SVB  = (float*)(wsb + 42467328 + 18874368); // +18MiB   : 3.54MB  -> ends +22.4MB
  float* LOGD = (float*)(wsb + 42467328 + 23068672); // +22MiB   : 3.10MB  -> ends +26.2MB
  short* XB   = (short*)(wsb + 84934656);
  short* FUS  = (short*)(wsb + 84934656);
  short* HIDB = (short*)(wsb + 84934656 + 16777216);
  short* P1B  = (short*)(wsb + 84934656 + 16777216);
  // Weights (persistent)
  char* wb = wsb + 115867648;
  short* W1W   = (short*)(wb + 0);        // 256x352
  short* WIHW  = (short*)(wb + 180224);   // 768x256
  short* WHHW  = (short*)(wb + 573440);   // 768x256
  short* WP2W  = (short*)(wb + 966656);   // 128x256
  short* WPQK  = (short*)(wb + 1032192);  // 512x256
  short* WGDW  = (short*)(wb + 1294336);  // 512x288
  short* WFW   = (short*)(wb + 1589248);  // 128x512
  float* BPQKb = (float*)(wb + 1720320);  // 384
  float* BGD   = (float*)(wb + 1721856);  // 512
  float* BF2   = (float*)(wb + 1723904);  // 128

  float* out = (float*)d_out;
  float* H   = out + (size_t)ROWS * 33;   // h output region, fp32

  // 1. bf16 conversions / packing (acts + weights, one launch)
  conv_all<<<69028, 256, 0, stream>>>(inputs, hidden,
                                      W1, Wih, Whh, Wp1, Wp2, Wq, Wk, Wg1, Wd1,
                                      Wg2, Wd2, bp1, bq, bg1, bd1, bg2, bd2,
                                      XINB, HIDB,
                                      W1W, WIHW, WHHW, WP2W, WPQK, WGDW, WFW,
                                      BPQKb, BGD, BF2);
  // 2. X = relu(inputs @ W1^T + b1)   K=352 -> 5x64 + 32 tail (48KB LDS)
  gemm_mfma<1, 1><<<dim3(216, 2), 256, 49152, stream>>>(XINB, 352, W1W, 352, b1, XB, 256, 256, 352);
  // 3. GI = X @ Wih^T + bih           K=256 (32KB LDS)
  gemm_mfma<0, 1><<<dim3(216, 6), 256, 32768, stream>>>(XB, 256, WIHW, 256, bih, GIB, 768, 768, 256);
  // 4. GH = hidden @ Whh^T + bhh      K=256
  gemm_mfma<0, 1><<<dim3(216, 6), 256, 32768, stream>>>(HIDB, 256, WHHW, 256, bhh, GHB, 768, 768, 256);
  // 5. GRU -> H (fp32, d_out) + fusion[:,0:256] (bf16)
  gru_kernel<<<6912, 256, 0, stream>>>(GIB, GHB, hidden, H, FUS);
  // 6. [P1 | QK] = h @ [Wp1; Wq; Wk_h]^T + [bp1; bq; 0]   K=256
  gemm_pqk<<<dim3(216, 3), 256, 32768, stream>>>(FUS, WPQK, BPQKb, P1B, QKB);
  // 7. logits = P1 @ Wp2^T + bp2      K=256
  gemm_mfma<0, 0><<<dim3(216, 1), 256, 32768, stream>>>(P1B, 256, WP2W, 256, bp2, LOG, 33, 33, 256);
  // 8. sender values
  sv_kernel<<<6912, 256, 0, stream>>>(LOG, Wv, bv, SVB);
  // 9. attention v6 -> fusion[:,256:288]
  attn4_kernel<<<dim3(1024, 7), 256, 0, stream>>>(QKB, rel, Wk, bk, SVB, null_key,
                                                  null_value, ln_g, ln_b, FUS);
  // 10. [G1 | D1] = relu(fusion @ [Wg1; Wd1]^T + [bg1; bd1])  K=288 -> 4x64+32
  gemm_mfma<1, 1><<<dim3(216, 4), 256, 49152, stream>>>(FUS, 288, WGDW, 288, BGD, GDB, 512, 512, 288);
  // 11. GDf = GD @ WFW^T + [bg2; bd2] K=512
  gemm_mfma<0, 0><<<dim3(216, 1), 256, 32768, stream>>>(GDB, 512, WFW, 512, BF2, LOGD, 28, 28, 512);
  // 12. final fuse
  fuse_kernel<<<3564, 256, 0, stream>>>(LOGD, LOG, out);
}